// Round 7
// baseline (186.162 us; speedup 1.0000x reference)
//
#include <hip/hip_runtime.h>
#include <hip/hip_fp16.h>

typedef float    f32x4 __attribute__((ext_vector_type(4)));
typedef _Float16 f16x2 __attribute__((ext_vector_type(2)));
typedef _Float16 f16x4 __attribute__((ext_vector_type(4)));
typedef _Float16 f16x8 __attribute__((ext_vector_type(8)));

#define BS 8
#define NN 2048
#define DK 128
#define DM 64
#define MIXOFF (1024 * DK)  // halfs between mix-0 and mix-1 rows of one batch
// log2(e) / sqrt(128): folds softmax temperature AND exp->exp2 conversion into Q
#define QSCALE 0.12751744116926208f

#define MFMA32(a, b, c) __builtin_amdgcn_mfma_f32_16x16x32_f16((a), (b), (c), 0, 0, 0)
#define EXP2(x) __builtin_amdgcn_exp2f(x)

__device__ __forceinline__ f16x2 pkrtz(float x, float y) {
  return __builtin_bit_cast(f16x2, __builtin_amdgcn_cvt_pkrtz(x, y));
}

// async global->LDS DMA, 16B per lane; no VGPR transit (allocator-proof)
__device__ __forceinline__ void load_lds16(const _Float16* g, _Float16* l) {
  __builtin_amdgcn_global_load_lds(
      (const __attribute__((address_space(1))) void*)(uintptr_t)g,
      (__attribute__((address_space(3))) void*)(uint32_t)(uintptr_t)l, 16, 0, 0);
}

// ---- fused prep: K f32->f16 (512 blk), V transpose 64x64 (512 blk), q-mean (64 blk) ----
__global__ void prep_k(const float* __restrict__ kt, _Float16* __restrict__ kh,
                       const float* __restrict__ vt, _Float16* __restrict__ vT,
                       const float* __restrict__ qt, float* __restrict__ partial) {
  __shared__ float tile[64][65];
  __shared__ float red[256];
  int blk = blockIdx.x;
  int t = threadIdx.x;
  if (blk < 512) {
    size_t base = (size_t)blk * 4096;
#pragma unroll
    for (int j = 0; j < 4; ++j) {
      size_t i = base + j * 1024 + t * 4;
      f32x4 v = *(const f32x4*)(kt + i);
      f16x4 h;
      h[0] = (_Float16)v[0]; h[1] = (_Float16)v[1];
      h[2] = (_Float16)v[2]; h[3] = (_Float16)v[3];
      *(f16x4*)(kh + i) = h;
    }
  } else if (blk < 1024) {
    int i2 = blk - 512;
    int b = i2 >> 6;
    int rem = i2 & 63;
    int j0 = (rem & 31) * 64;   // key tile
    int c0 = (rem >> 5) * 64;   // channel tile
    int tx = t & 63, ty = t >> 6;
    const float* src = vt + ((size_t)b * NN + j0) * DK + c0;
#pragma unroll
    for (int rr = 0; rr < 16; ++rr) {
      int row = ty * 16 + rr;
      tile[row][tx] = src[(size_t)row * DK + tx];
    }
    __syncthreads();
    _Float16* dst = vT + ((size_t)b * DK + c0) * NN + j0;
    int chl = t >> 4;
    int k4 = (t & 15) * 4;
#pragma unroll
    for (int r2 = 0; r2 < 4; ++r2) {
      int ch = r2 * 16 + chl;
      f16x4 h;
      h[0] = (_Float16)tile[k4 + 0][ch]; h[1] = (_Float16)tile[k4 + 1][ch];
      h[2] = (_Float16)tile[k4 + 2][ch]; h[3] = (_Float16)tile[k4 + 3][ch];
      *(f16x4*)(dst + (size_t)ch * NN + k4) = h;
    }
  } else {
    int i = blk - 1024;
    int b = i >> 3, seg = i & 7;
    int c = t & 127, h = t >> 7;
    const float* p = qt + ((size_t)b * NN + seg * 256 + h * 128) * DK + c;
    float s = 0.f;
#pragma unroll 8
    for (int n = 0; n < 128; ++n) s += p[(size_t)n * DK];
    red[t] = s;
    __syncthreads();
    if (t < 128) partial[(size_t)i * 128 + t] = red[t] + red[t + 128];
  }
}

// Stage step S (32 keys x both kh-halves = 32KB) into buffer BUF. 2048 16B units,
// 512 threads x 4: j0=K kh0, j1=V kh0, j2=K kh1, j3=V kh1 (same unit map as R6).
#define STAGE(BUF, S) do {                                                \
    _Float16* db_ = stg + (BUF) * 16384;                                  \
    load_lds16(khg + gK0 + (S) * 2048, db_ + t * 8);                      \
    load_lds16(vTg + gV0 + (S) * 32, db_ + 4096 + t * 8);                 \
    load_lds16(khg + gK1 + (S) * 2048, db_ + 8192 + t * 8);               \
    load_lds16(vTg + gV1 + (S) * 32, db_ + 12288 + t * 8);                \
  } while (0)

#define COMPUTE(BUF) do {                                                      \
    const _Float16* sb_ = stg + (BUF) * 16384 + khs * 8192;                    \
    f16x8 kf_[8];                                                              \
    kf_[0] = *(const f16x8*)(sb_ + kr0 + kA);                                  \
    kf_[1] = *(const f16x8*)(sb_ + kr0 + kB);                                  \
    kf_[2] = *(const f16x8*)(sb_ + 2048 + kr0 + kA);                           \
    kf_[3] = *(const f16x8*)(sb_ + 2048 + kr0 + kB);                           \
    kf_[4] = *(const f16x8*)(sb_ + kr1 + kA);                                  \
    kf_[5] = *(const f16x8*)(sb_ + kr1 + kB);                                  \
    kf_[6] = *(const f16x8*)(sb_ + 2048 + kr1 + kA);                           \
    kf_[7] = *(const f16x8*)(sb_ + 2048 + kr1 + kB);                           \
    f32x4 s_[2][2][2]; /* [u][m][subtile] */                                   \
    _Pragma("unroll")                                                          \
    for (int u = 0; u < 2; ++u) {                                              \
      s_[u][0][0] = MFMA32(kf_[1], qf[u][0][1], MFMA32(kf_[0], qf[u][0][0], z)); \
      s_[u][1][0] = MFMA32(kf_[3], qf[u][1][1], MFMA32(kf_[2], qf[u][1][0], z)); \
      s_[u][0][1] = MFMA32(kf_[5], qf[u][0][1], MFMA32(kf_[4], qf[u][0][0], z)); \
      s_[u][1][1] = MFMA32(kf_[7], qf[u][1][1], MFMA32(kf_[6], qf[u][1][0], z)); \
    }                                                                          \
    f16x8 vf_[8];                                                              \
    _Pragma("unroll")                                                          \
    for (int cc = 0; cc < 8; ++cc)                                             \
      vf_[cc] = *(const f16x8*)(sb_ + vbase + cc * 512);                       \
    _Pragma("unroll")                                                          \
    for (int u = 0; u < 2; ++u)                                                \
      _Pragma("unroll")                                                        \
      for (int m = 0; m < 2; ++m) {                                            \
        float e0 = EXP2(s_[u][m][0][0]), e1 = EXP2(s_[u][m][0][1]);            \
        float e2 = EXP2(s_[u][m][0][2]), e3 = EXP2(s_[u][m][0][3]);            \
        float e4 = EXP2(s_[u][m][1][0]), e5 = EXP2(s_[u][m][1][1]);            \
        float e6 = EXP2(s_[u][m][1][2]), e7 = EXP2(s_[u][m][1][3]);            \
        lsum[u][m] += ((e0 + e1) + (e2 + e3)) + ((e4 + e5) + (e6 + e7));       \
        union { f16x8 v; f16x2 h[4]; } w_;                                     \
        w_.h[0] = pkrtz(e0, e1); w_.h[1] = pkrtz(e2, e3);                      \
        w_.h[2] = pkrtz(e4, e5); w_.h[3] = pkrtz(e6, e7);                      \
        _Pragma("unroll")                                                      \
        for (int cc = 0; cc < 8; ++cc)                                         \
          acc[u][m][cc] = MFMA32(vf_[cc], w_.v, acc[u][m][cc]);                \
      }                                                                        \
  } while (0)

// ---------------- main: mixture flash attention -------------------------------
// grid 256 x 512thr (1 blk/CU, 2 waves/SIMD): b=blk&7, qb=blk>>3 (64 q/block).
// Wave role (qp,khs,par): 32 q (2 tiles), key-half khs, computes alternate steps
// (par). Per step stage 32KB (both kh tiles, dbuf=64KB static LDS); each tile is
// read by only 2 waves -> LDS reads 2MB/CU (was 4MB in R6, the binding pipe).
// Idle-parity waves give each SIMD a second wave to hide MFMA->exp->PV latency.
// Same proven fragment layouts/swizzles as R6. Merge 4 duplicates per q via LDS
// store+atomicAdd in two mix-passes (fits 64KB); prior softmax redundant/block.
__global__ __launch_bounds__(512, 2) void attn_k(const float* __restrict__ qt,
                                                 const _Float16* __restrict__ khg,
                                                 const _Float16* __restrict__ vTg,
                                                 const float* __restrict__ kern,
                                                 const float* __restrict__ partial,
                                                 float* __restrict__ out) {
  __shared__ __align__(16) char smem[65536];
  _Float16* stg = (_Float16*)smem;  // [2][16384] halfs = 2 x 32KB
  const int b = blockIdx.x & 7;
  const int qb = blockIdx.x >> 3;
  const int t = threadIdx.x;
  const int wv = t >> 6;
  const int qp = wv & 1, khs = (wv >> 1) & 1, par = wv >> 2;
  const int lane = t & 63;
  const int quad = lane >> 4, l16 = lane & 15;
  const int perm = ((l16 >> 2) << 3) | (l16 & 3);
  const int bq = b * (NN * DK);
  const int bV = b * (DK * NN);

  // Q fragments: f32 load + scale + pack to f16 in-register; u = 16-q subtile
  f16x8 qf[2][2][2];  // [u][mix][chunk]
#pragma unroll
  for (int u = 0; u < 2; ++u)
#pragma unroll
    for (int m = 0; m < 2; ++m)
#pragma unroll
      for (int c = 0; c < 2; ++c) {
        const float* qp_ = qt + bq + m * MIXOFF +
                           (qb * 64 + qp * 32 + u * 16 + l16) * DM + quad * 8 + c * 32;
        f32x4 v0 = *(const f32x4*)qp_;
        f32x4 v1 = *(const f32x4*)(qp_ + 4);
        union { f16x8 v; f16x2 h[4]; } w;
        w.h[0] = pkrtz(v0[0] * QSCALE, v0[1] * QSCALE);
        w.h[1] = pkrtz(v0[2] * QSCALE, v0[3] * QSCALE);
        w.h[2] = pkrtz(v1[0] * QSCALE, v1[1] * QSCALE);
        w.h[3] = pkrtz(v1[2] * QSCALE, v1[3] * QSCALE);
        qf[u][m][c] = w.v;
      }

  // staging offsets (halfs), same swizzle map as R6
  const int mixu = (t >> 8) & 1;
  const int w8 = t & 255;
  const int rK = w8 >> 3;
  const int uuK = (w8 & 7) ^ ((rK & 3) ^ ((rK >> 3) << 1));
  const int chV = t >> 2;
  const int uuV = (t & 3) ^ ((chV + (chV >> 2)) & 3);
  const int gK0 = bq + mixu * MIXOFF + rK * 64 + uuK * 8;
  const int gK1 = gK0 + 1024 * 64;
  const int gV0 = bV + chV * NN + uuV * 8;
  const int gV1 = gV0 + 1024;

  // LDS read offsets (halfs), swizzles matching the unit map (proven in R6)
  const int gK = (l16 & 3) ^ ((l16 >> 2) << 1);
  const int hV = (l16 + (l16 >> 2)) & 3;
  const int kA = (quad ^ gK) * 8;
  const int kB = ((quad + 4) ^ gK) * 8;
  const int kr0 = perm * 64;
  const int kr1 = (perm + 4) * 64;
  const int vbase = 4096 + l16 * 32 + (quad ^ hV) * 8;

  const f32x4 z = {0.f, 0.f, 0.f, 0.f};
  f32x4 acc[2][2][8];  // [u][mix][cc]
  float lsum[2][2] = {{0.f, 0.f}, {0.f, 0.f}};
#pragma unroll
  for (int u = 0; u < 2; ++u)
#pragma unroll
    for (int m = 0; m < 2; ++m)
#pragma unroll
      for (int cc = 0; cc < 8; ++cc) acc[u][m][cc] = z;

  STAGE(0, 0);
  for (int s = 0; s < 32; s += 2) {
    __syncthreads();  // tile s landed; reads of buf1 (step s-1) done
    STAGE(1, s + 1);
    if (par == 0) COMPUTE(0);
    __syncthreads();  // tile s+1 landed; reads of buf0 (step s) done
    if (s + 2 < 32) STAGE(0, s + 2);
    if (par == 1) COMPUTE(1);
  }
  __syncthreads();

  // ---- epilogue (overlays staging LDS) ----
  float* obuf = (float*)smem;                  // [64][132]; slot 128 = l
  float* barL = (float*)(smem + 33792);        // [8][128]
  float* lgp = (float*)(smem + 37888);
  float* exq = (float*)(smem + 37952);
  float* prp = (float*)(smem + 38016);

  // prior softmax (redundant per block)
  for (int e = t; e < 1024; e += 512) {
    int bb = e >> 7, c = e & 127;
    float ss = 0.f;
#pragma unroll
    for (int seg = 0; seg < 8; ++seg) ss += partial[(size_t)(bb * 8 + seg) * 128 + c];
    barL[e] = ss * (1.0f / 2048.0f);
  }
  __syncthreads();
  if (t < 16) {
    int m = t >> 3, bb = t & 7;
    float ss = 0.f;
    for (int c = 0; c < DK; ++c) ss += kern[m * DK + c] * barL[bb * 128 + c];
    lgp[t] = ss;
  }
  __syncthreads();
  if (t < 16) {
    int m = t >> 3;
    float mx = lgp[m * 8];
    for (int i = 1; i < 8; ++i) mx = fmaxf(mx, lgp[m * 8 + i]);
    exq[t] = __expf(lgp[t] - mx);
  }
  __syncthreads();
  if (t < 16) {
    int m = t >> 3;
    float sm = 0.f;
    for (int i = 0; i < 8; ++i) sm += exq[m * 8 + i];
    prp[t] = exq[t] / sm;  // flat[m*8+b]; read as [b*2+m] (TF reshape quirk)
  }
  __syncthreads();
  const float w0 = prp[b * 2 + 0], w1 = prp[b * 2 + 1];
  const int row = t >> 3;
  const int cb = (t & 7) * 16;
  f32x4 o0[4];

#pragma unroll
  for (int M = 0; M < 2; ++M) {
    if (t < 64) obuf[t * 132 + 128] = 0.f;
    if (wv < 2) {  // role (khs=0,par=0): plain stores seed the merge
#pragma unroll
      for (int u = 0; u < 2; ++u) {
        int r_ = (qp * 32 + u * 16 + l16) * 132;
#pragma unroll
        for (int cc = 0; cc < 8; ++cc)
          *(f32x4*)&obuf[r_ + cc * 16 + quad * 4] = acc[u][M][cc];
      }
    }
    __syncthreads();
    if (wv >= 2) {
#pragma unroll
      for (int u = 0; u < 2; ++u) {
        int r_ = (qp * 32 + u * 16 + l16) * 132;
#pragma unroll
        for (int cc = 0; cc < 8; ++cc)
#pragma unroll
          for (int e = 0; e < 4; ++e)
            atomicAdd(&obuf[r_ + cc * 16 + quad * 4 + e], acc[u][M][cc][e]);
      }
    }
#pragma unroll
    for (int u = 0; u < 2; ++u)
      atomicAdd(&obuf[(qp * 32 + u * 16 + l16) * 132 + 128], lsum[u][M]);
    __syncthreads();
    if (M == 0) {
      float r0 = w0 / obuf[row * 132 + 128];
#pragma unroll
      for (int g = 0; g < 4; ++g) {
        f32x4 v = *(const f32x4*)&obuf[row * 132 + cb + g * 4];
#pragma unroll
        for (int e = 0; e < 4; ++e) o0[g][e] = v[e] * r0;
      }
      __syncthreads();  // reads done before pass-1 overwrites
    } else {
      float r1 = w1 / obuf[row * 132 + 128];
      float* op = out + ((size_t)b * NN + qb * 64 + row) * DK + cb;
#pragma unroll
      for (int g = 0; g < 4; ++g) {
        f32x4 v = *(const f32x4*)&obuf[row * 132 + cb + g * 4];
        f32x4 o;
#pragma unroll
        for (int e = 0; e < 4; ++e) o[e] = o0[g][e] + v[e] * r1;
        *(f32x4*)(op + g * 4) = o;
      }
    }
  }
}

extern "C" void kernel_launch(void* const* d_in, const int* in_sizes, int n_in,
                              void* d_out, int out_size, void* d_ws, size_t ws_size,
                              hipStream_t stream) {
  const float* qt = (const float*)d_in[0];
  const float* kt = (const float*)d_in[1];
  const float* vt = (const float*)d_in[2];
  const float* kern = (const float*)d_in[3];
  float* out = (float*)d_out;

  char* ws = (char*)d_ws;
  float* partial = (float*)ws;               // 64*128 floats (32 KB)
  _Float16* khp = (_Float16*)(ws + 65536);   // 2M halfs (4 MB)
  _Float16* vTp = khp + (size_t)BS * NN * DK;

  prep_k<<<dim3(1088), dim3(256), 0, stream>>>(kt, khp, vt, vTp, qt, partial);
  attn_k<<<dim3(256), dim3(512), 0, stream>>>(qt, khp, vTp, kern, partial, out);
}

// Round 8
// 118.155 us; speedup vs baseline: 1.5756x; 1.5756x over previous
//
#include <hip/hip_runtime.h>
#include <hip/hip_fp16.h>

typedef float    f32x4 __attribute__((ext_vector_type(4)));
typedef _Float16 f16x2 __attribute__((ext_vector_type(2)));
typedef _Float16 f16x4 __attribute__((ext_vector_type(4)));
typedef _Float16 f16x8 __attribute__((ext_vector_type(8)));

#define BS 8
#define NN 2048
#define DK 128
#define DM 64
#define MIXOFF (1024 * DK)  // halfs between mix-0 and mix-1 rows of one batch
// log2(e) / sqrt(128): folds softmax temperature AND exp->exp2 conversion into Q
#define QSCALE 0.12751744116926208f

#define MFMA32(a, b, c) __builtin_amdgcn_mfma_f32_16x16x32_f16((a), (b), (c), 0, 0, 0)
#define EXP2(x) __builtin_amdgcn_exp2f(x)

__device__ __forceinline__ f16x2 pkrtz(float x, float y) {
  return __builtin_bit_cast(f16x2, __builtin_amdgcn_cvt_pkrtz(x, y));
}

// async global->LDS DMA, 16B per lane; no VGPR transit (allocator-proof)
__device__ __forceinline__ void load_lds16(const _Float16* g, _Float16* l) {
  __builtin_amdgcn_global_load_lds(
      (const __attribute__((address_space(1))) void*)(uintptr_t)g,
      (__attribute__((address_space(3))) void*)(uint32_t)(uintptr_t)l, 16, 0, 0);
}

// ---- fused prep: K f32->f16 (512 blk), V transpose 64x64 (512 blk), q-mean (64 blk) ----
__global__ void prep_k(const float* __restrict__ kt, _Float16* __restrict__ kh,
                       const float* __restrict__ vt, _Float16* __restrict__ vT,
                       const float* __restrict__ qt, float* __restrict__ partial) {
  __shared__ float tile[64][65];
  __shared__ float red[256];
  int blk = blockIdx.x;
  int t = threadIdx.x;
  if (blk < 512) {
    size_t base = (size_t)blk * 4096;
#pragma unroll
    for (int j = 0; j < 4; ++j) {
      size_t i = base + j * 1024 + t * 4;
      f32x4 v = *(const f32x4*)(kt + i);
      f16x4 h;
      h[0] = (_Float16)v[0]; h[1] = (_Float16)v[1];
      h[2] = (_Float16)v[2]; h[3] = (_Float16)v[3];
      *(f16x4*)(kh + i) = h;
    }
  } else if (blk < 1024) {
    int i2 = blk - 512;
    int b = i2 >> 6;
    int rem = i2 & 63;
    int j0 = (rem & 31) * 64;   // key tile
    int c0 = (rem >> 5) * 64;   // channel tile
    int tx = t & 63, ty = t >> 6;
    const float* src = vt + ((size_t)b * NN + j0) * DK + c0;
#pragma unroll
    for (int rr = 0; rr < 16; ++rr) {
      int row = ty * 16 + rr;
      tile[row][tx] = src[(size_t)row * DK + tx];
    }
    __syncthreads();
    _Float16* dst = vT + ((size_t)b * DK + c0) * NN + j0;
    int chl = t >> 4;
    int k4 = (t & 15) * 4;
#pragma unroll
    for (int r2 = 0; r2 < 4; ++r2) {
      int ch = r2 * 16 + chl;
      f16x4 h;
      h[0] = (_Float16)tile[k4 + 0][ch]; h[1] = (_Float16)tile[k4 + 1][ch];
      h[2] = (_Float16)tile[k4 + 2][ch]; h[3] = (_Float16)tile[k4 + 3][ch];
      *(f16x4*)(dst + (size_t)ch * NN + k4) = h;
    }
  } else {
    int i = blk - 1024;
    int b = i >> 3, seg = i & 7;
    int c = t & 127, h = t >> 7;
    const float* p = qt + ((size_t)b * NN + seg * 256 + h * 128) * DK + c;
    float s = 0.f;
#pragma unroll 8
    for (int n = 0; n < 128; ++n) s += p[(size_t)n * DK];
    red[t] = s;
    __syncthreads();
    if (t < 128) partial[(size_t)i * 128 + t] = red[t] + red[t + 128];
  }
}

// Stage one 32-key tile (16KB: K both mixes 8KB + V 8KB) into buffer BUF.
// 1024 16B units, 512 threads x 2. Same verified unit map/swizzles as R6.
#define STAGE(BUF, S) do {                                 \
    _Float16* db_ = stg + (BUF) * 8192;                    \
    load_lds16(khg + gKst + (S) * 2048, db_ + t * 8);      \
    load_lds16(vTg + gVst + (S) * 32, db_ + 4096 + t * 8); \
  } while (0)

// ---------------- main: mixture flash attention -------------------------------
// grid 256 x 512thr (1 blk/CU, 2 waves/SIMD): b=blk&7, qb=blk>>3 (64 q/block).
// Wave = (mix m, q-tile u): ALL 8 waves compute EVERY step (R7's parity gating
// serialized SIMD partners across the barrier -> 2x regression). SIMD partners
// (same u, different m) run concurrent independent chains -> latency hiding that
// R6's 1-wave/SIMD lacked (R6: ~900 cyc/iter naked dep-chain latency).
// Same verified layouts: S^T via mfma(K-perm rows, Q^T); P^T D-frag == x32
// B-operand; V^T f16x8 A-frags; XOR-swizzled LDS. l via lane sums + 2 shfl_xor.
// Mix merge in epilogue: m=0 waves write r0*acc to LDS, m=1 add r1*acc, store.
__global__ __launch_bounds__(512, 2) void attn_k(const float* __restrict__ qt,
                                                 const _Float16* __restrict__ khg,
                                                 const _Float16* __restrict__ vTg,
                                                 const float* __restrict__ kern,
                                                 const float* __restrict__ partial,
                                                 float* __restrict__ out) {
  __shared__ __align__(16) char smem[40960];
  _Float16* stg = (_Float16*)smem;  // [2][8192] halfs = 2 x 16KB
  const int b = blockIdx.x & 7;
  const int qb = blockIdx.x >> 3;
  const int t = threadIdx.x;
  const int wv = t >> 6;
  const int m = wv >> 2;       // mixture handled by this wave
  const int u = wv & 3;        // 16-query tile within block
  const int lane = t & 63;
  const int quad = lane >> 4, l16 = lane & 15;
  const int perm = ((l16 >> 2) << 3) | (l16 & 3);
  const int bq = b * (NN * DK);
  const int bV = b * (DK * NN);

  // Q fragments for this wave's (m, u): f32 load + scale + pack in-register
  f16x8 qf[2];
#pragma unroll
  for (int c = 0; c < 2; ++c) {
    const float* qp_ = qt + bq + m * MIXOFF +
                       (qb * 64 + u * 16 + l16) * DM + quad * 8 + c * 32;
    f32x4 v0 = *(const f32x4*)qp_;
    f32x4 v1 = *(const f32x4*)(qp_ + 4);
    union { f16x8 v; f16x2 h[4]; } w;
    w.h[0] = pkrtz(v0[0] * QSCALE, v0[1] * QSCALE);
    w.h[1] = pkrtz(v0[2] * QSCALE, v0[3] * QSCALE);
    w.h[2] = pkrtz(v1[0] * QSCALE, v1[1] * QSCALE);
    w.h[3] = pkrtz(v1[2] * QSCALE, v1[3] * QSCALE);
    qf[c] = w.v;
  }

  // staging offsets (halfs): thread t stages K unit t and V unit t (R6 map)
  const int mixu = t >> 8;
  const int qq8 = t & 255;
  const int rK = qq8 >> 3;
  const int uuK = (qq8 & 7) ^ ((rK & 3) ^ ((rK >> 3) << 1));
  const int chV = t >> 2;
  const int uuV = (t & 3) ^ ((chV + (chV >> 2)) & 3);
  const int gKst = bq + mixu * MIXOFF + rK * 64 + uuK * 8;
  const int gVst = bV + chV * NN + uuV * 8;

  // LDS read offsets (halfs), swizzles matching the unit map (verified R6)
  const int gK = (l16 & 3) ^ ((l16 >> 2) << 1);
  const int hV = (l16 + (l16 >> 2)) & 3;
  const int kA = (quad ^ gK) * 8;
  const int kB = ((quad + 4) ^ gK) * 8;
  const int kr0 = m * 2048 + perm * 64;
  const int kr1 = m * 2048 + (perm + 4) * 64;
  const int vbase = 4096 + l16 * 32 + (quad ^ hV) * 8;

  const f32x4 z = {0.f, 0.f, 0.f, 0.f};
  f32x4 acc[8];
  float lsum = 0.f;
#pragma unroll
  for (int cc = 0; cc < 8; ++cc) acc[cc] = z;

  STAGE(0, 0);
  int buf = 0;
  for (int s = 0; s < 64; ++s) {
    __syncthreads();  // tile s landed; reads of buf^1 (step s-1) done
    if (s + 1 < 64) STAGE(buf ^ 1, s + 1);
    const _Float16* sb_ = stg + buf * 8192;
    f16x8 kf0 = *(const f16x8*)(sb_ + kr0 + kA);
    f16x8 kf1 = *(const f16x8*)(sb_ + kr0 + kB);
    f16x8 kf2 = *(const f16x8*)(sb_ + kr1 + kA);
    f16x8 kf3 = *(const f16x8*)(sb_ + kr1 + kB);
    f32x4 s0 = MFMA32(kf1, qf[1], MFMA32(kf0, qf[0], z));
    f32x4 s1 = MFMA32(kf3, qf[1], MFMA32(kf2, qf[0], z));
    f16x8 vf[8];
#pragma unroll
    for (int cc = 0; cc < 8; ++cc) vf[cc] = *(const f16x8*)(sb_ + vbase + cc * 512);
    float e0 = EXP2(s0[0]), e1 = EXP2(s0[1]), e2 = EXP2(s0[2]), e3 = EXP2(s0[3]);
    float e4 = EXP2(s1[0]), e5 = EXP2(s1[1]), e6 = EXP2(s1[2]), e7 = EXP2(s1[3]);
    lsum += ((e0 + e1) + (e2 + e3)) + ((e4 + e5) + (e6 + e7));
    union { f16x8 v; f16x2 h[4]; } w;
    w.h[0] = pkrtz(e0, e1); w.h[1] = pkrtz(e2, e3);
    w.h[2] = pkrtz(e4, e5); w.h[3] = pkrtz(e6, e7);
#pragma unroll
    for (int cc = 0; cc < 8; ++cc) acc[cc] = MFMA32(vf[cc], w.v, acc[cc]);
    buf ^= 1;
  }
  __syncthreads();  // all tile reads done; epilogue overlays staging LDS

  // ---- epilogue ----
  float* obuf = (float*)smem;                  // [64][132] floats (33792 B)
  float* barL = (float*)(smem + 33792);        // [8][128]
  float* lgp = (float*)(smem + 37888);
  float* exq = (float*)(smem + 37952);
  float* prp = (float*)(smem + 38016);

  // prior softmax (redundant per block)
  for (int e = t; e < 1024; e += 512) {
    int bb = e >> 7, c = e & 127;
    float ss = 0.f;
#pragma unroll
    for (int seg = 0; seg < 8; ++seg) ss += partial[(size_t)(bb * 8 + seg) * 128 + c];
    barL[e] = ss * (1.0f / 2048.0f);
  }
  __syncthreads();
  if (t < 16) {
    int mm = t >> 3, bb = t & 7;
    float ss = 0.f;
    for (int c = 0; c < DK; ++c) ss += kern[mm * DK + c] * barL[bb * 128 + c];
    lgp[t] = ss;
  }
  __syncthreads();
  if (t < 16) {
    int mm = t >> 3;
    float mx = lgp[mm * 8];
    for (int i = 1; i < 8; ++i) mx = fmaxf(mx, lgp[mm * 8 + i]);
    exq[t] = __expf(lgp[t] - mx);
  }
  __syncthreads();
  if (t < 16) {
    int mm = t >> 3;
    float sm = 0.f;
    for (int i = 0; i < 8; ++i) sm += exq[mm * 8 + i];
    prp[t] = exq[t] / sm;  // flat[m*8+b]; read as [b*2+m] (TF reshape quirk)
  }
  __syncthreads();

  // l for this lane's query: sum partials across quads (lanes xor 16, 32)
  lsum += __shfl_xor(lsum, 16);
  lsum += __shfl_xor(lsum, 32);
  const float r_ = prp[b * 2 + m] / lsum;

  const int orow = (u * 16 + l16) * 132;
  if (m == 0) {
#pragma unroll
    for (int cc = 0; cc < 8; ++cc) {
      f32x4 o;
#pragma unroll
      for (int e = 0; e < 4; ++e) o[e] = acc[cc][e] * r_;
      *(f32x4*)&obuf[orow + cc * 16 + quad * 4] = o;
    }
  }
  __syncthreads();
  if (m == 1) {
#pragma unroll
    for (int cc = 0; cc < 8; ++cc) {
      f32x4 o = *(const f32x4*)&obuf[orow + cc * 16 + quad * 4];
#pragma unroll
      for (int e = 0; e < 4; ++e) o[e] += acc[cc][e] * r_;
      *(f32x4*)&obuf[orow + cc * 16 + quad * 4] = o;
    }
  }
  __syncthreads();
  const int row = t >> 3;
  const int cb = (t & 7) * 16;
  float* op = out + ((size_t)b * NN + qb * 64 + row) * DK + cb;
#pragma unroll
  for (int g = 0; g < 4; ++g)
    *(f32x4*)(op + g * 4) = *(const f32x4*)&obuf[row * 132 + cb + g * 4];
}

extern "C" void kernel_launch(void* const* d_in, const int* in_sizes, int n_in,
                              void* d_out, int out_size, void* d_ws, size_t ws_size,
                              hipStream_t stream) {
  const float* qt = (const float*)d_in[0];
  const float* kt = (const float*)d_in[1];
  const float* vt = (const float*)d_in[2];
  const float* kern = (const float*)d_in[3];
  float* out = (float*)d_out;

  char* ws = (char*)d_ws;
  float* partial = (float*)ws;               // 64*128 floats (32 KB)
  _Float16* khp = (_Float16*)(ws + 65536);   // 2M halfs (4 MB)
  _Float16* vTp = khp + (size_t)BS * NN * DK;

  prep_k<<<dim3(1088), dim3(256), 0, stream>>>(kt, khp, vt, vTp, qt, partial);
  attn_k<<<dim3(256), dim3(512), 0, stream>>>(qt, khp, vTp, kern, partial, out);
}